// Round 1
// baseline (233.077 us; speedup 1.0000x reference)
//
#include <hip/hip_runtime.h>
#include <hip/hip_bf16.h>

typedef __hip_bfloat16 bf16;
typedef __attribute__((ext_vector_type(8))) short short8;
typedef __attribute__((ext_vector_type(4))) float f32x4;

#define DEV static __device__ __forceinline__

static constexpr int SEQ = 2048;
static constexpr int DM  = 1024;
static constexpr int NH  = 16;
static constexpr int HD  = 64;
static constexpr int WIN = 2048;
static constexpr int PAD = 1024;   // WIN/2

// async global->LDS, 16B per lane; LDS dest = wave-uniform base + lane*16
DEV void async16(const void* g, void* l) {
  __builtin_amdgcn_global_load_lds(
      (__attribute__((address_space(1))) void*)(g),
      (__attribute__((address_space(3))) void*)(l), 16, 0, 0);
}

// ---------------------------------------------------------------- K0: f32 -> bf16 convert (x, w_qkv, w_proj)
__global__ __launch_bounds__(256) void k_cvt(const float* __restrict__ x,
                                             const float* __restrict__ wq,
                                             const float* __restrict__ wp,
                                             bf16* __restrict__ xb,
                                             bf16* __restrict__ wqb,
                                             bf16* __restrict__ wpb) {
  const int NX = SEQ * DM, NQ = 3 * DM * DM, NP = DM * DM;
  const int tot = (NX + NQ + NP) >> 2;
  const int stride = gridDim.x * 256;
  for (int i = blockIdx.x * 256 + threadIdx.x; i < tot; i += stride) {
    int e = i << 2;
    const float* s; bf16* d; int o;
    if (e < NX)            { s = x;  d = xb;  o = e; }
    else if (e < NX + NQ)  { s = wq; d = wqb; o = e - NX; }
    else                   { s = wp; d = wpb; o = e - NX - NQ; }
    float4 v = *(const float4*)(s + o);
    __align__(8) bf16 t4[4] = {__float2bfloat16(v.x), __float2bfloat16(v.y),
                               __float2bfloat16(v.z), __float2bfloat16(v.w)};
    *(uint2*)(d + o) = *(uint2*)t4;
  }
}

// ---------------------------------------------------------------- shared GEMM core: C[m][n] = sum_k A[m][k]*B[n][k]
// 128x128 tile, BK=64, 256 threads (4 waves as 2x2 of 64x64), 16x16x32 bf16 MFMA.
DEV void gemm_core(const bf16* __restrict__ A, const bf16* __restrict__ B,
                   int m0, int n0, int K, int tid, bf16* As, bf16* Bs,
                   f32x4 (&acc)[4][4]) {
  const int lane = tid & 63, wid = tid >> 6;
  const int wm = wid >> 1, wn = wid & 1;
  const int l15 = lane & 15, l4 = lane >> 4;
  for (int k0 = 0; k0 < K; k0 += 64) {
    __syncthreads();
    #pragma unroll
    for (int it = 0; it < 4; ++it) {
      int rb = it * 32 + wid * 8;
      int r  = rb + (lane >> 3);
      int c  = (lane & 7) * 8;
      async16(A + (size_t)(m0 + r) * K + k0 + c, As + rb * 64);
      async16(B + (size_t)(n0 + r) * K + k0 + c, Bs + rb * 64);
    }
    asm volatile("s_waitcnt vmcnt(0)" ::: "memory");
    __syncthreads();
    #pragma unroll
    for (int kk = 0; kk < 2; ++kk) {
      short8 a[4], b[4];
      #pragma unroll
      for (int im = 0; im < 4; ++im)
        a[im] = *(const short8*)(As + (wm * 64 + im * 16 + l15) * 64 + kk * 32 + l4 * 8);
      #pragma unroll
      for (int in = 0; in < 4; ++in)
        b[in] = *(const short8*)(Bs + (wn * 64 + in * 16 + l15) * 64 + kk * 32 + l4 * 8);
      #pragma unroll
      for (int im = 0; im < 4; ++im)
        #pragma unroll
        for (int in = 0; in < 4; ++in)
          acc[im][in] = __builtin_amdgcn_mfma_f32_16x16x32_bf16(a[im], b[in], acc[im][in], 0, 0, 0);
    }
  }
}

// ---------------------------------------------------------------- K1: qkv GEMM + scatter to per-head q(scaled)/k/v
__global__ __launch_bounds__(256) void k_gemm_qkv(const bf16* __restrict__ A,
                                                  const bf16* __restrict__ B,
                                                  const float* __restrict__ bias,
                                                  bf16* __restrict__ qo,
                                                  bf16* __restrict__ ko,
                                                  bf16* __restrict__ vo) {
  __shared__ bf16 As[128 * 64], Bs[128 * 64];
  const int tid = threadIdx.x, lane = tid & 63;
  const int wid = tid >> 6, wm = wid >> 1, wn = wid & 1;
  const int l15 = lane & 15, l4 = lane >> 4;
  const int m0 = blockIdx.x * 128, n0 = blockIdx.y * 128;
  f32x4 acc[4][4] = {};
  gemm_core(A, B, m0, n0, DM, tid, As, Bs, acc);
  #pragma unroll
  for (int im = 0; im < 4; ++im)
    #pragma unroll
    for (int in = 0; in < 4; ++in) {
      int col = n0 + wn * 64 + in * 16 + l15;
      float bval = bias[col];
      int t = col >> 10, h = (col >> 6) & 15, dd = col & 63;
      #pragma unroll
      for (int r = 0; r < 4; ++r) {
        int row = m0 + wm * 64 + im * 16 + l4 * 4 + r;
        float v = acc[im][in][r] + bval;
        size_t idx = ((size_t)h * SEQ + row) * HD + dd;
        if (t == 0)      qo[idx] = __float2bfloat16(v * 0.125f);  // fold hd^-0.5
        else if (t == 1) ko[idx] = __float2bfloat16(v);
        else             vo[idx] = __float2bfloat16(v);
      }
    }
}

// ---------------------------------------------------------------- K1b: transpose v [h][j][d] -> vT [h][d][j]
__global__ __launch_bounds__(256) void k_vt(const bf16* __restrict__ v, bf16* __restrict__ vT) {
  const int h = blockIdx.x >> 5;
  const int j0 = (blockIdx.x & 31) * 64;
  __shared__ bf16 t[64 * 64];
  const int tid = threadIdx.x;
  #pragma unroll
  for (int it = 0; it < 2; ++it) {
    int c = it * 256 + tid;
    int r = c >> 3, cg = c & 7;
    short8 val = *(const short8*)&v[((size_t)h * SEQ + j0 + r) * HD + cg * 8];
    int pg = cg ^ ((r >> 3) & 7);                 // XOR swizzle keyed on r>>3
    *(short8*)&t[r * 64 + pg * 8] = val;
  }
  __syncthreads();
  #pragma unroll
  for (int it = 0; it < 2; ++it) {
    int c = it * 256 + tid;
    int dd = c >> 3, jj0 = (c & 7) * 8;
    union { unsigned short u[8]; short8 v8; } o;
    #pragma unroll
    for (int e = 0; e < 8; ++e) {
      int j = jj0 + e;
      int pg = (dd >> 3) ^ ((j >> 3) & 7);
      o.u[e] = *(unsigned short*)&t[j * 64 + pg * 8 + (dd & 7)];
    }
    *(short8*)&vT[((size_t)h * HD + dd) * SEQ + j0 + jj0] = o.v8;
  }
}

// ---------------------------------------------------------------- K2: fused banded scores + softmax + attn write + PV
// 1 wave per block; block = (head h, 32 query rows i0..i0+31).
// j' = i + j (absolute k_pad index). Tiles tt=0..64 cover j' in [i0, i0+2080).
__global__ __launch_bounds__(64) void k_attn(const bf16* __restrict__ q,
                                             const bf16* __restrict__ kkk,
                                             const bf16* __restrict__ vT,
                                             float* __restrict__ attn,
                                             bf16* __restrict__ ao) {
  const int h  = blockIdx.x >> 6;
  const int i0 = (blockIdx.x & 63) << 5;
  const int lane = threadIdx.x;
  const int l15 = lane & 15, l4 = lane >> 4;

  __shared__ bf16 KP[2][32 * 64];   // K tile, [j'loc][d], XOR-swizzled 16B groups
  __shared__ bf16 VTT[2][64 * 32];  // vT tile, [d][j], linear (conflict-free)
  __shared__ bf16 JB[32 * 64];      // rolling j-space attn (bf16), XOR-swizzled

  // Q fragments (scale already folded in), rows i0..i0+31, k = d
  short8 qf[2][2];
  #pragma unroll
  for (int fm = 0; fm < 2; ++fm)
    #pragma unroll
    for (int kg = 0; kg < 2; ++kg)
      qf[fm][kg] = *(const short8*)&q[((size_t)h * SEQ + i0 + fm * 16 + l15) * HD + kg * 32 + l4 * 8];

  const bf16* kbase = kkk + (size_t)h * SEQ * HD;
  const bf16* vbase = vT + (size_t)h * HD * SEQ;

  auto stage_kp = [&](int tt, int buf) {
    #pragma unroll
    for (int it = 0; it < 4; ++it) {
      int r  = it * 8 + (lane >> 3);
      int cg = lane & 7;
      int jp = i0 + tt * 32 + r;                 // absolute j'
      int krow = jp - PAD;                       // k row; clamp (pad handled analytically)
      krow = krow < 0 ? 0 : (krow > SEQ - 1 ? SEQ - 1 : krow);
      int sc = (cg ^ (r & 7)) * 8;               // pre-swizzled global source (rule #21)
      async16(kbase + (size_t)krow * HD + sc, (void*)&KP[buf][it * 8 * 64]);
    }
  };
  auto stage_vt = [&](int jb, int buf) {
    #pragma unroll
    for (int it = 0; it < 4; ++it) {
      int d  = it * 16 + (lane >> 2);
      int cc = (lane & 3) * 8;
      async16(vbase + (size_t)d * SEQ + jb + cc, (void*)&VTT[buf][it * 16 * 32]);
    }
  };

  // ---------------- phase 1: row sums of exp(s) over the full window
  float psum[2][4] = {};
  stage_kp(0, 0);
  for (int tt = 0; tt <= 64; ++tt) {
    stage_kp(tt < 64 ? tt + 1 : 64, (tt + 1) & 1);
    asm volatile("s_waitcnt vmcnt(4)" ::: "memory");
    const int buf = tt & 1;
    f32x4 sf[2][2] = {};
    #pragma unroll
    for (int kg = 0; kg < 2; ++kg) {
      short8 kf[2];
      #pragma unroll
      for (int fn = 0; fn < 2; ++fn) {
        int jl = fn * 16 + l15;
        int pg = (kg * 4 + l4) ^ (jl & 7);
        kf[fn] = *(const short8*)&KP[buf][jl * 64 + pg * 8];
      }
      #pragma unroll
      for (int fm = 0; fm < 2; ++fm)
        #pragma unroll
        for (int fn = 0; fn < 2; ++fn)
          sf[fm][fn] = __builtin_amdgcn_mfma_f32_16x16x32_bf16(qf[fm][kg], kf[fn], sf[fm][fn], 0, 0, 0);
    }
    #pragma unroll
    for (int fm = 0; fm < 2; ++fm)
      #pragma unroll
      for (int fn = 0; fn < 2; ++fn) {
        int jl = fn * 16 + l15;
        int jpabs = i0 + tt * 32 + jl;
        bool pad = (jpabs < PAD) || (jpabs >= PAD + SEQ);
        #pragma unroll
        for (int r = 0; r < 4; ++r) {
          int iloc = fm * 16 + l4 * 4 + r;
          int j = tt * 32 + jl - iloc;
          float e = pad ? 1.0f : __expf(sf[fm][fn][r]);  // padded k row => score 0 => exp=1
          if ((unsigned)j < (unsigned)WIN) psum[fm][r] += e;
        }
      }
  }
  float inv[2][4];
  #pragma unroll
  for (int fm = 0; fm < 2; ++fm)
    #pragma unroll
    for (int r = 0; r < 4; ++r) {
      float s = psum[fm][r];
      s += __shfl_xor(s, 1); s += __shfl_xor(s, 2);
      s += __shfl_xor(s, 4); s += __shfl_xor(s, 8);
      inv[fm][r] = __builtin_amdgcn_rcpf(s);
    }

  // ---------------- phase 2: recompute, normalize, write attn, fused PV
  f32x4 oacc[2][4] = {};
  stage_kp(0, 0);
  for (int tt = 0; tt <= 64; ++tt) {
    stage_kp(tt < 64 ? tt + 1 : 64, (tt + 1) & 1);
    {
      int jbn = tt * 32; if (jbn > SEQ - 32) jbn = SEQ - 32;   // vT tile for PV at iter tt+1
      stage_vt(jbn, (tt + 1) & 1);
    }
    asm volatile("s_waitcnt vmcnt(8)" ::: "memory");
    const int buf = tt & 1;
    f32x4 sf[2][2] = {};
    #pragma unroll
    for (int kg = 0; kg < 2; ++kg) {
      short8 kf[2];
      #pragma unroll
      for (int fn = 0; fn < 2; ++fn) {
        int jl = fn * 16 + l15;
        int pg = (kg * 4 + l4) ^ (jl & 7);
        kf[fn] = *(const short8*)&KP[buf][jl * 64 + pg * 8];
      }
      #pragma unroll
      for (int fm = 0; fm < 2; ++fm)
        #pragma unroll
        for (int fn = 0; fn < 2; ++fn)
          sf[fm][fn] = __builtin_amdgcn_mfma_f32_16x16x32_bf16(qf[fm][kg], kf[fn], sf[fm][fn], 0, 0, 0);
    }
    #pragma unroll
    for (int fm = 0; fm < 2; ++fm)
      #pragma unroll
      for (int fn = 0; fn < 2; ++fn) {
        int jl = fn * 16 + l15;
        int jpabs = i0 + tt * 32 + jl;
        bool pad = (jpabs < PAD) || (jpabs >= PAD + SEQ);
        #pragma unroll
        for (int r = 0; r < 4; ++r) {
          int iloc = fm * 16 + l4 * 4 + r;
          int j = tt * 32 + jl - iloc;
          float e = pad ? 1.0f : __expf(sf[fm][fn][r]);
          float val = e * inv[fm][r];
          if ((unsigned)j < (unsigned)WIN) {
            attn[((size_t)(h * SEQ + i0 + iloc)) * WIN + j] = val;
            int pg = ((j & 63) >> 3) ^ (iloc & 7);
            JB[iloc * 64 + pg * 8 + (j & 7)] = __float2bfloat16(val);
          }
        }
      }
    if (tt >= 1) {
      const int jb = (tt - 1) * 32;
      const int vbuf = tt & 1;                 // staged at iter tt-1
      const int gjbase = (jb & 63) >> 3;       // 0 or 4
      short8 af[2];
      #pragma unroll
      for (int fm = 0; fm < 2; ++fm) {
        int row = fm * 16 + l15;
        int pg = (gjbase + l4) ^ (row & 7);
        af[fm] = *(const short8*)&JB[row * 64 + pg * 8];
      }
      short8 bv[4];
      #pragma unroll
      for (int nd = 0; nd < 4; ++nd)
        bv[nd] = *(const short8*)&VTT[vbuf][(nd * 16 + l15) * 32 + l4 * 8];
      #pragma unroll
      for (int fm = 0; fm < 2; ++fm)
        #pragma unroll
        for (int nd = 0; nd < 4; ++nd)
          oacc[fm][nd] = __builtin_amdgcn_mfma_f32_16x16x32_bf16(af[fm], bv[nd], oacc[fm][nd], 0, 0, 0);
    }
  }
  // write attention output rows (pre-proj), layout [i][h*64+dd]
  #pragma unroll
  for (int fm = 0; fm < 2; ++fm)
    #pragma unroll
    for (int nd = 0; nd < 4; ++nd)
      #pragma unroll
      for (int r = 0; r < 4; ++r) {
        int i  = i0 + fm * 16 + l4 * 4 + r;
        int dd = nd * 16 + l15;
        ao[(size_t)i * DM + h * HD + dd] = __float2bfloat16(oacc[fm][nd][r]);
      }
}

// ---------------------------------------------------------------- K4: proj GEMM -> d_out (f32)
__global__ __launch_bounds__(256) void k_gemm_proj(const bf16* __restrict__ A,
                                                   const bf16* __restrict__ B,
                                                   const float* __restrict__ bias,
                                                   float* __restrict__ out) {
  __shared__ bf16 As[128 * 64], Bs[128 * 64];
  const int tid = threadIdx.x, lane = tid & 63;
  const int wid = tid >> 6, wm = wid >> 1, wn = wid & 1;
  const int l15 = lane & 15, l4 = lane >> 4;
  const int m0 = blockIdx.x * 128, n0 = blockIdx.y * 128;
  f32x4 acc[4][4] = {};
  gemm_core(A, B, m0, n0, DM, tid, As, Bs, acc);
  #pragma unroll
  for (int im = 0; im < 4; ++im)
    #pragma unroll
    for (int in = 0; in < 4; ++in) {
      int col = n0 + wn * 64 + in * 16 + l15;
      float bval = bias[col];
      #pragma unroll
      for (int r = 0; r < 4; ++r) {
        int row = m0 + wm * 64 + im * 16 + l4 * 4 + r;
        out[(size_t)row * DM + col] = acc[im][in][r] + bval;
      }
    }
}

// ---------------------------------------------------------------- launch
extern "C" void kernel_launch(void* const* d_in, const int* in_sizes, int n_in,
                              void* d_out, int out_size, void* d_ws, size_t ws_size,
                              hipStream_t stream) {
  (void)in_sizes; (void)n_in; (void)out_size; (void)ws_size;
  const float* x  = (const float*)d_in[0];
  const float* wq = (const float*)d_in[1];
  const float* bq = (const float*)d_in[2];
  const float* wp = (const float*)d_in[3];
  const float* bp = (const float*)d_in[4];
  float* out  = (float*)d_out;
  float* attn = out + (size_t)SEQ * DM;

  char* ws = (char*)d_ws;
  bf16* xb   = (bf16*)(ws + (size_t) 0);          // 4 MB  x bf16
  bf16* wqb  = (bf16*)(ws + ((size_t)4  << 20));  // 6 MB  w_qkv bf16
  bf16* wpb  = (bf16*)(ws + ((size_t)10 << 20));  // 2 MB  w_proj bf16
  bf16* qarr = (bf16*)(ws + ((size_t)12 << 20));  // 4 MB  q [h][i][d] (scaled)
  bf16* karr = (bf16*)(ws + ((size_t)16 << 20));  // 4 MB  k [h][j][d]
  bf16* varr = (bf16*)(ws + ((size_t)20 << 20));  // 4 MB  v [h][j][d]
  bf16* vt   = (bf16*)(ws + ((size_t)24 << 20));  // 4 MB  vT [h][d][j]
  bf16* ao   = (bf16*)(ws + ((size_t)28 << 20));  // 4 MB  attn-out rows [i][h*64+d]

  k_cvt<<<dim3(1024), dim3(256), 0, stream>>>(x, wq, wp, xb, wqb, wpb);
  k_gemm_qkv<<<dim3(16, 24), dim3(256), 0, stream>>>(xb, wqb, bq, qarr, karr, varr);
  k_vt<<<dim3(512), dim3(256), 0, stream>>>(varr, vt);
  k_attn<<<dim3(1024), dim3(64), 0, stream>>>(qarr, karr, vt, attn, ao);
  k_gemm_proj<<<dim3(16, 8), dim3(256), 0, stream>>>(ao, wpb, bp, out);
}

// Round 2
// 229.862 us; speedup vs baseline: 1.0140x; 1.0140x over previous
//
#include <hip/hip_runtime.h>
#include <hip/hip_bf16.h>

typedef __hip_bfloat16 bf16;
typedef __attribute__((ext_vector_type(8))) short short8;
typedef __attribute__((ext_vector_type(4))) float f32x4;

#define DEV static __device__ __forceinline__

static constexpr int SEQ = 2048;
static constexpr int DM  = 1024;
static constexpr int NH  = 16;
static constexpr int HD  = 64;
static constexpr int WIN = 2048;
static constexpr int PAD = 1024;   // WIN/2

// async global->LDS, 16B per lane; LDS dest = wave-uniform base + lane*16
DEV void async16(const void* g, void* l) {
  __builtin_amdgcn_global_load_lds(
      (__attribute__((address_space(1))) void*)(g),
      (__attribute__((address_space(3))) void*)(l), 16, 0, 0);
}

// ---------------------------------------------------------------- K0: f32 -> bf16 convert (x, w_qkv, w_proj)
__global__ __launch_bounds__(256) void k_cvt(const float* __restrict__ x,
                                             const float* __restrict__ wq,
                                             const float* __restrict__ wp,
                                             bf16* __restrict__ xb,
                                             bf16* __restrict__ wqb,
                                             bf16* __restrict__ wpb) {
  const int NX = SEQ * DM, NQ = 3 * DM * DM, NP = DM * DM;
  const int tot = (NX + NQ + NP) >> 2;
  const int stride = gridDim.x * 256;
  for (int i = blockIdx.x * 256 + threadIdx.x; i < tot; i += stride) {
    int e = i << 2;
    const float* s; bf16* d; int o;
    if (e < NX)            { s = x;  d = xb;  o = e; }
    else if (e < NX + NQ)  { s = wq; d = wqb; o = e - NX; }
    else                   { s = wp; d = wpb; o = e - NX - NQ; }
    float4 v = *(const float4*)(s + o);
    __align__(8) bf16 t4[4] = {__float2bfloat16(v.x), __float2bfloat16(v.y),
                               __float2bfloat16(v.z), __float2bfloat16(v.w)};
    *(uint2*)(d + o) = *(uint2*)t4;
  }
}

// ---------------------------------------------------------------- shared GEMM core: C[m][n] = sum_k A[m][k]*B[n][k]
DEV void gemm_core(const bf16* __restrict__ A, const bf16* __restrict__ B,
                   int m0, int n0, int K, int tid, bf16* As, bf16* Bs,
                   f32x4 (&acc)[4][4]) {
  const int lane = tid & 63, wid = tid >> 6;
  const int wm = wid >> 1, wn = wid & 1;
  const int l15 = lane & 15, l4 = lane >> 4;
  for (int k0 = 0; k0 < K; k0 += 64) {
    __syncthreads();
    #pragma unroll
    for (int it = 0; it < 4; ++it) {
      int rb = it * 32 + wid * 8;
      int r  = rb + (lane >> 3);
      int c  = (lane & 7) * 8;
      async16(A + (size_t)(m0 + r) * K + k0 + c, As + rb * 64);
      async16(B + (size_t)(n0 + r) * K + k0 + c, Bs + rb * 64);
    }
    asm volatile("s_waitcnt vmcnt(0)" ::: "memory");
    __syncthreads();
    #pragma unroll
    for (int kk = 0; kk < 2; ++kk) {
      short8 a[4], b[4];
      #pragma unroll
      for (int im = 0; im < 4; ++im)
        a[im] = *(const short8*)(As + (wm * 64 + im * 16 + l15) * 64 + kk * 32 + l4 * 8);
      #pragma unroll
      for (int in = 0; in < 4; ++in)
        b[in] = *(const short8*)(Bs + (wn * 64 + in * 16 + l15) * 64 + kk * 32 + l4 * 8);
      #pragma unroll
      for (int im = 0; im < 4; ++im)
        #pragma unroll
        for (int in = 0; in < 4; ++in)
          acc[im][in] = __builtin_amdgcn_mfma_f32_16x16x32_bf16(a[im], b[in], acc[im][in], 0, 0, 0);
    }
  }
}

// ---------------------------------------------------------------- K1: qkv GEMM + scatter to per-head q(scaled)/k/v
__global__ __launch_bounds__(256) void k_gemm_qkv(const bf16* __restrict__ A,
                                                  const bf16* __restrict__ B,
                                                  const float* __restrict__ bias,
                                                  bf16* __restrict__ qo,
                                                  bf16* __restrict__ ko,
                                                  bf16* __restrict__ vo) {
  __shared__ bf16 As[128 * 64], Bs[128 * 64];
  const int tid = threadIdx.x, lane = tid & 63;
  const int wid = tid >> 6, wm = wid >> 1, wn = wid & 1;
  const int l15 = lane & 15, l4 = lane >> 4;
  const int m0 = blockIdx.x * 128, n0 = blockIdx.y * 128;
  f32x4 acc[4][4] = {};
  gemm_core(A, B, m0, n0, DM, tid, As, Bs, acc);
  #pragma unroll
  for (int im = 0; im < 4; ++im)
    #pragma unroll
    for (int in = 0; in < 4; ++in) {
      int col = n0 + wn * 64 + in * 16 + l15;
      float bval = bias[col];
      int t = col >> 10, h = (col >> 6) & 15, dd = col & 63;
      #pragma unroll
      for (int r = 0; r < 4; ++r) {
        int row = m0 + wm * 64 + im * 16 + l4 * 4 + r;
        float v = acc[im][in][r] + bval;
        size_t idx = ((size_t)h * SEQ + row) * HD + dd;
        if (t == 0)      qo[idx] = __float2bfloat16(v * 0.125f);  // fold hd^-0.5
        else if (t == 1) ko[idx] = __float2bfloat16(v);
        else             vo[idx] = __float2bfloat16(v);
      }
    }
}

// ---------------------------------------------------------------- K1b: transpose v [h][j][d] -> vT [h][d][j]
__global__ __launch_bounds__(256) void k_vt(const bf16* __restrict__ v, bf16* __restrict__ vT) {
  const int h = blockIdx.x >> 5;
  const int j0 = (blockIdx.x & 31) * 64;
  __shared__ bf16 t[64 * 64];
  const int tid = threadIdx.x;
  #pragma unroll
  for (int it = 0; it < 2; ++it) {
    int c = it * 256 + tid;
    int r = c >> 3, cg = c & 7;
    short8 val = *(const short8*)&v[((size_t)h * SEQ + j0 + r) * HD + cg * 8];
    int pg = cg ^ ((r >> 3) & 7);
    *(short8*)&t[r * 64 + pg * 8] = val;
  }
  __syncthreads();
  #pragma unroll
  for (int it = 0; it < 2; ++it) {
    int c = it * 256 + tid;
    int dd = c >> 3, jj0 = (c & 7) * 8;
    union { unsigned short u[8]; short8 v8; } o;
    #pragma unroll
    for (int e = 0; e < 8; ++e) {
      int j = jj0 + e;
      int pg = (dd >> 3) ^ ((j >> 3) & 7);
      o.u[e] = *(unsigned short*)&t[j * 64 + pg * 8 + (dd & 7)];
    }
    *(short8*)&vT[((size_t)h * HD + dd) * SEQ + j0 + jj0] = o.v8;
  }
}

// ---------------------------------------------------------------- K1c: zero aof accumulator
__global__ __launch_bounds__(256) void k_zero(float* __restrict__ p) {
  int i = blockIdx.x * 256 + threadIdx.x;   // grid covers NH*SEQ*HD/4
  ((float4*)p)[i] = float4{0.f, 0.f, 0.f, 0.f};
}

// ---------------------------------------------------------------- attn helpers
DEV void stage_kp(const bf16* kbase, int i0, int tt, int lane, bf16* dst) {
  #pragma unroll
  for (int it = 0; it < 4; ++it) {
    int r  = it * 8 + (lane >> 3);
    int cg = lane & 7;
    int jp = i0 + tt * 32 + r;                 // absolute j'
    int krow = jp - PAD;                       // clamp; pad handled analytically
    krow = krow < 0 ? 0 : (krow > SEQ - 1 ? SEQ - 1 : krow);
    int sc = (cg ^ (r & 7)) * 8;               // pre-swizzled global source
    async16(kbase + (size_t)krow * HD + sc, dst + it * 8 * 64);
  }
}

DEV void qk_mfma(const bf16* KPb, const short8 (&qf)[2][2], int l15, int l4,
                 f32x4 (&sf)[2][2]) {
  #pragma unroll
  for (int kg = 0; kg < 2; ++kg) {
    short8 kf[2];
    #pragma unroll
    for (int fn = 0; fn < 2; ++fn) {
      int jl = fn * 16 + l15;
      int pg = (kg * 4 + l4) ^ (jl & 7);
      kf[fn] = *(const short8*)&KPb[jl * 64 + pg * 8];
    }
    #pragma unroll
    for (int fm = 0; fm < 2; ++fm)
      #pragma unroll
      for (int fn = 0; fn < 2; ++fn)
        sf[fm][fn] = __builtin_amdgcn_mfma_f32_16x16x32_bf16(qf[fm][kg], kf[fn], sf[fm][fn], 0, 0, 0);
  }
}

// ---------------------------------------------------------------- K2a: partial exp-sums per window chunk
// grid: 16 heads x 64 itiles x 4 chunks; 1 wave per block.
__global__ __launch_bounds__(64) void k_attn1(const bf16* __restrict__ q,
                                              const bf16* __restrict__ kkk,
                                              float* __restrict__ psums) {
  const int c  = blockIdx.x & 3;
  const int i0 = ((blockIdx.x >> 2) & 63) << 5;
  const int h  = blockIdx.x >> 8;
  const int lane = threadIdx.x;
  const int l15 = lane & 15, l4 = lane >> 4;
  constexpr int st[5] = {0, 17, 33, 49, 65};
  const int c0 = st[c], c1 = st[c + 1];

  __shared__ bf16 KP[2][32 * 64];

  short8 qf[2][2];
  #pragma unroll
  for (int fm = 0; fm < 2; ++fm)
    #pragma unroll
    for (int kg = 0; kg < 2; ++kg)
      qf[fm][kg] = *(const short8*)&q[((size_t)h * SEQ + i0 + fm * 16 + l15) * HD + kg * 32 + l4 * 8];

  const bf16* kbase = kkk + (size_t)h * SEQ * HD;

  float psum[2][4] = {};
  stage_kp(kbase, i0, c0, lane, KP[c0 & 1]);
  for (int tt = c0; tt < c1; ++tt) {
    int nxt = (tt + 1 < c1) ? tt + 1 : tt;
    stage_kp(kbase, i0, nxt, lane, KP[(tt + 1) & 1]);
    asm volatile("s_waitcnt vmcnt(4)" ::: "memory");
    f32x4 sf[2][2] = {};
    qk_mfma(KP[tt & 1], qf, l15, l4, sf);
    #pragma unroll
    for (int fm = 0; fm < 2; ++fm)
      #pragma unroll
      for (int fn = 0; fn < 2; ++fn) {
        int jl = fn * 16 + l15;
        int jpabs = i0 + tt * 32 + jl;
        bool pad = (jpabs < PAD) || (jpabs >= PAD + SEQ);
        #pragma unroll
        for (int r = 0; r < 4; ++r) {
          int iloc = fm * 16 + l4 * 4 + r;
          int j = tt * 32 + jl - iloc;
          float e = pad ? 1.0f : __expf(sf[fm][fn][r]);
          if ((unsigned)j < (unsigned)WIN) psum[fm][r] += e;
        }
      }
  }
  #pragma unroll
  for (int fm = 0; fm < 2; ++fm)
    #pragma unroll
    for (int r = 0; r < 4; ++r) {
      float s = psum[fm][r];
      s += __shfl_xor(s, 1); s += __shfl_xor(s, 2);
      s += __shfl_xor(s, 4); s += __shfl_xor(s, 8);
      if (l15 == 0)
        psums[((size_t)c * NH + h) * SEQ + i0 + fm * 16 + l4 * 4 + r] = s;
    }
}

// ---------------------------------------------------------------- K2b: recompute + normalize + attn write + partial PV
// grid: 16 heads x 64 itiles x 4 chunks; 1 wave per block.
__global__ __launch_bounds__(64) void k_attn2(const bf16* __restrict__ q,
                                              const bf16* __restrict__ kkk,
                                              const bf16* __restrict__ vT,
                                              const float* __restrict__ psums,
                                              float* __restrict__ attn,
                                              float* __restrict__ aof) {
  const int c  = blockIdx.x & 3;
  const int i0 = ((blockIdx.x >> 2) & 63) << 5;
  const int h  = blockIdx.x >> 8;
  const int lane = threadIdx.x;
  const int l15 = lane & 15, l4 = lane >> 4;
  const int c0 = c * 16, c1 = c0 + 16;
  const int ahi = (c == 3) ? 65 : c1;          // attn-write tile range [c0, ahi)

  __shared__ bf16 KP[2][32 * 64];
  __shared__ bf16 JB[32 * 64];                 // rolling j-space attn (bf16), XOR-swizzled

  // inverse row sums
  float inv[2][4];
  #pragma unroll
  for (int fm = 0; fm < 2; ++fm)
    #pragma unroll
    for (int r = 0; r < 4; ++r) {
      int row = i0 + fm * 16 + l4 * 4 + r;
      float s = 0.f;
      #pragma unroll
      for (int cc = 0; cc < 4; ++cc)
        s += psums[((size_t)cc * NH + h) * SEQ + row];
      inv[fm][r] = __builtin_amdgcn_rcpf(s);
    }

  short8 qf[2][2];
  #pragma unroll
  for (int fm = 0; fm < 2; ++fm)
    #pragma unroll
    for (int kg = 0; kg < 2; ++kg)
      qf[fm][kg] = *(const short8*)&q[((size_t)h * SEQ + i0 + fm * 16 + l15) * HD + kg * 32 + l4 * 8];

  const bf16* kbase = kkk + (size_t)h * SEQ * HD;
  const bf16* vbase = vT + (size_t)h * HD * SEQ;

  f32x4 oacc[2][4] = {};
  stage_kp(kbase, i0, c0, lane, KP[0]);        // c0 even -> buf 0
  for (int tt = c0; tt <= c1; ++tt) {
    // PV B-fragments for this iteration, direct from global vT (L2-resident)
    short8 bv[4];
    if (tt > c0) {
      int jb = (tt - 1) * 32;
      #pragma unroll
      for (int nd = 0; nd < 4; ++nd)
        bv[nd] = *(const short8*)&vbase[(size_t)(nd * 16 + l15) * SEQ + jb + l4 * 8];
    }
    int nxt = (tt < c1) ? tt + 1 : tt;
    stage_kp(kbase, i0, nxt, lane, KP[(tt + 1) & 1]);
    asm volatile("s_waitcnt vmcnt(4)" ::: "memory");

    f32x4 sf[2][2] = {};
    qk_mfma(KP[tt & 1], qf, l15, l4, sf);

    #pragma unroll
    for (int fm = 0; fm < 2; ++fm)
      #pragma unroll
      for (int fn = 0; fn < 2; ++fn) {
        int jl = fn * 16 + l15;
        int jpabs = i0 + tt * 32 + jl;
        bool pad = (jpabs < PAD) || (jpabs >= PAD + SEQ);
        #pragma unroll
        for (int r = 0; r < 4; ++r) {
          int iloc = fm * 16 + l4 * 4 + r;
          int j = tt * 32 + jl - iloc;
          float e = pad ? 1.0f : __expf(sf[fm][fn][r]);
          float val = e * inv[fm][r];
          if ((unsigned)j < (unsigned)WIN) {
            if (tt < ahi)
              attn[((size_t)(h * SEQ + i0 + iloc)) * WIN + j] = val;
            int pg = ((j & 63) >> 3) ^ (iloc & 7);
            JB[iloc * 64 + pg * 8 + (j & 7)] = __float2bfloat16(val);
          }
        }
      }
    if (tt > c0) {
      const int jb = (tt - 1) * 32;
      const int gjbase = (jb & 63) >> 3;       // 0 or 4
      short8 af[2];
      #pragma unroll
      for (int fm = 0; fm < 2; ++fm) {
        int row = fm * 16 + l15;
        int pg = (gjbase + l4) ^ (row & 7);
        af[fm] = *(const short8*)&JB[row * 64 + pg * 8];
      }
      #pragma unroll
      for (int fm = 0; fm < 2; ++fm)
        #pragma unroll
        for (int nd = 0; nd < 4; ++nd)
          oacc[fm][nd] = __builtin_amdgcn_mfma_f32_16x16x32_bf16(af[fm], bv[nd], oacc[fm][nd], 0, 0, 0);
    }
  }
  // accumulate partial O into f32 buffer (cross-chunk reduction)
  #pragma unroll
  for (int fm = 0; fm < 2; ++fm)
    #pragma unroll
    for (int nd = 0; nd < 4; ++nd)
      #pragma unroll
      for (int r = 0; r < 4; ++r) {
        int i  = i0 + fm * 16 + l4 * 4 + r;
        int dd = nd * 16 + l15;
        atomicAdd(&aof[((size_t)h * SEQ + i) * HD + dd], oacc[fm][nd][r]);
      }
}

// ---------------------------------------------------------------- K2c: aof f32 [h][i][dd] -> ao bf16 [i][h*64+dd]
__global__ __launch_bounds__(256) void k_ored(const float* __restrict__ aof,
                                              bf16* __restrict__ ao) {
  int f = blockIdx.x * 256 + threadIdx.x;      // float4 index, NH*SEQ*HD/4 total
  int e = f << 2;
  int h  = e >> 17;                            // SEQ*HD = 131072
  int i  = (e >> 6) & (SEQ - 1);
  int dd = e & 63;
  float4 v = ((const float4*)aof)[f];
  __align__(8) bf16 t4[4] = {__float2bfloat16(v.x), __float2bfloat16(v.y),
                             __float2bfloat16(v.z), __float2bfloat16(v.w)};
  *(uint2*)&ao[(size_t)i * DM + h * HD + dd] = *(uint2*)t4;
}

// ---------------------------------------------------------------- K4: proj GEMM -> d_out (f32)
__global__ __launch_bounds__(256) void k_gemm_proj(const bf16* __restrict__ A,
                                                   const bf16* __restrict__ B,
                                                   const float* __restrict__ bias,
                                                   float* __restrict__ out) {
  __shared__ bf16 As[128 * 64], Bs[128 * 64];
  const int tid = threadIdx.x, lane = tid & 63;
  const int wid = tid >> 6, wm = wid >> 1, wn = wid & 1;
  const int l15 = lane & 15, l4 = lane >> 4;
  const int m0 = blockIdx.x * 128, n0 = blockIdx.y * 128;
  f32x4 acc[4][4] = {};
  gemm_core(A, B, m0, n0, DM, tid, As, Bs, acc);
  #pragma unroll
  for (int im = 0; im < 4; ++im)
    #pragma unroll
    for (int in = 0; in < 4; ++in) {
      int col = n0 + wn * 64 + in * 16 + l15;
      float bval = bias[col];
      #pragma unroll
      for (int r = 0; r < 4; ++r) {
        int row = m0 + wm * 64 + im * 16 + l4 * 4 + r;
        out[(size_t)row * DM + col] = acc[im][in][r] + bval;
      }
    }
}

// ---------------------------------------------------------------- launch
extern "C" void kernel_launch(void* const* d_in, const int* in_sizes, int n_in,
                              void* d_out, int out_size, void* d_ws, size_t ws_size,
                              hipStream_t stream) {
  (void)in_sizes; (void)n_in; (void)out_size; (void)ws_size;
  const float* x  = (const float*)d_in[0];
  const float* wq = (const float*)d_in[1];
  const float* bq = (const float*)d_in[2];
  const float* wp = (const float*)d_in[3];
  const float* bp = (const float*)d_in[4];
  float* out  = (float*)d_out;
  float* attn = out + (size_t)SEQ * DM;

  char* ws = (char*)d_ws;
  bf16* xb    = (bf16*)(ws + (size_t) 0);          // 4 MB  x bf16            [dead after qkv gemm]
  bf16* wqb   = (bf16*)(ws + ((size_t)4  << 20));  // 6 MB  w_qkv bf16        [dead after qkv gemm]
  bf16* wpb   = (bf16*)(ws + ((size_t)10 << 20));  // 2 MB  w_proj bf16
  bf16* qarr  = (bf16*)(ws + ((size_t)12 << 20));  // 4 MB  q [h][i][d] (scaled)
  bf16* karr  = (bf16*)(ws + ((size_t)16 << 20));  // 4 MB  k [h][j][d]
  bf16* varr  = (bf16*)(ws + ((size_t)20 << 20));  // 4 MB  v [h][j][d]
  bf16* vt    = (bf16*)(ws + ((size_t)24 << 20));  // 4 MB  vT [h][d][j]
  bf16* ao    = (bf16*)(ws + ((size_t)28 << 20));  // 4 MB  attn-out rows [i][h*64+d]
  float* aof  = (float*)(ws + (size_t)0);          // 8 MB  f32 O accum (overlays xb+wqb, dead by then)
  float* psums= (float*)(ws + ((size_t)8 << 20));  // 512KB partial sums (overlays wqb tail, dead by then)

  k_cvt<<<dim3(1024), dim3(256), 0, stream>>>(x, wq, wp, xb, wqb, wpb);
  k_gemm_qkv<<<dim3(16, 24), dim3(256), 0, stream>>>(xb, wqb, bq, qarr, karr, varr);
  k_vt<<<dim3(512), dim3(256), 0, stream>>>(varr, vt);
  k_zero<<<dim3(NH * SEQ * HD / 4 / 256), dim3(256), 0, stream>>>(aof);
  k_attn1<<<dim3(4096), dim3(64), 0, stream>>>(qarr, karr, psums);
  k_attn2<<<dim3(4096), dim3(64), 0, stream>>>(qarr, karr, vt, psums, attn, aof);
  k_ored<<<dim3(NH * SEQ * HD / 4 / 256), dim3(256), 0, stream>>>(aof, ao);
  k_gemm_proj<<<dim3(16, 8), dim3(256), 0, stream>>>(ao, wpb, bp, out);
}